// Round 1
// baseline (1317.198 us; speedup 1.0000x reference)
//
#include <hip/hip_runtime.h>

#define N_ROWS 32768
#define K_CODES 4096
#define D_DIM 256

// ---- workspace layout (bytes) ----
#define WS_COUNTS   0          // float[4096]
#define WS_LOSSP    16384      // float[32768]
#define WS_PARTD    147456     // float[2*32768]
#define WS_PARTK    409600     // int[2*32768]
#define WS_DW       671744     // float[1048576]
#define WS_Z2       4866048    // float[32768]
#define WS_E2       4997120    // float[4096]
// total ~5.0 MB

// ---------------------------------------------------------------------------
// K1: z2[n] = np.sum(z*z, -1), e2[k] = np.sum(w*w, -1), replicating numpy's
// pairwise summation exactly: n=256 -> sum(0:128)+sum(128:256), each 128-block
// via 8 accumulators then ((r0+r1)+(r2+r3))+((r4+r5)+(r6+r7)).
// ---------------------------------------------------------------------------
__global__ void k1_norms(const float* __restrict__ z, const float* __restrict__ w,
                         float* __restrict__ z2, float* __restrict__ e2)
{
#pragma clang fp contract(off)
    int gid = blockIdx.x * blockDim.x + threadIdx.x;
    const float* row;
    float* outp;
    if (gid < N_ROWS) { row = z + (size_t)gid * D_DIM; outp = z2 + gid; }
    else if (gid < N_ROWS + K_CODES) { row = w + (size_t)(gid - N_ROWS) * D_DIM; outp = e2 + (gid - N_ROWS); }
    else return;

    float total = 0.0f;
    for (int half = 0; half < 2; half++) {
        const float* x = row + half * 128;
        float r[8];
#pragma unroll
        for (int j = 0; j < 8; j++) { float v = x[j]; r[j] = v * v; }
        for (int i = 8; i < 128; i += 8) {
#pragma unroll
            for (int j = 0; j < 8; j++) { float v = x[i + j]; r[j] += v * v; }
        }
        float s = ((r[0] + r[1]) + (r[2] + r[3])) + ((r[4] + r[5]) + (r[6] + r[7]));
        if (half == 0) total = s; else total = total + s;
    }
    *outp = total;
}

// ---------------------------------------------------------------------------
// K2: fused distance GEMM + running argmin.
// Exactness: each dot(n,k) is ONE sequential fp32 FMA chain over d=0..255
// (bit-identical to BLAS sgemm accumulation). d = fl(fl(z2 - 2*t) + e2),
// argmin = first index of min (strict < while scanning k ascending;
// lexicographic (d,k) merges across threads/halves).
// Tile: 128 rows x 128 codes, 256 threads, 8x8 micro-tile, DC=32 d-chunks,
// double-buffered LDS. Grid: (32768/128, 2 K-halves) = 512 blocks (2/CU).
// ---------------------------------------------------------------------------
#define BN 128
#define BK 128
#define DC 32
#define KHALF 2048

__global__ __launch_bounds__(256, 2) void k2_argmin(
    const float* __restrict__ z, const float* __restrict__ w,
    const float* __restrict__ z2, const float* __restrict__ e2,
    float* __restrict__ part_d, int* __restrict__ part_k)
{
    __shared__ float As[2][DC][BN];
    __shared__ float Bs[2][DC][BK];
    const int tid = threadIdx.x;
    const int tx = tid & 15, ty = tid >> 4;
    const int rowBase = blockIdx.x * BN;
    const int kBase0 = blockIdx.y * KHALF;

    float best[8]; int bestk[8];
#pragma unroll
    for (int i = 0; i < 8; i++) { best[i] = __builtin_inff(); bestk[i] = 0; }
    float z2r[8];
#pragma unroll
    for (int i = 0; i < 8; i++) z2r[i] = z2[rowBase + ty * 8 + i];

    float acc[8][8];
    float e2c[8];

    // stage chunk 0 (kt=0, ch=0) into buf 0
    {
        float4 va[4], vb[4];
#pragma unroll
        for (int it = 0; it < 4; it++) {
            int f = it * 256 + tid;
            int r = f >> 3, d4 = f & 7;
            va[it] = *(const float4*)&z[(size_t)(rowBase + r) * D_DIM + d4 * 4];
            vb[it] = *(const float4*)&w[(size_t)(kBase0 + r) * D_DIM + d4 * 4];
        }
#pragma unroll
        for (int it = 0; it < 4; it++) {
            int f = it * 256 + tid;
            int r = f >> 3, d4 = f & 7;
            As[0][d4 * 4 + 0][r] = va[it].x; As[0][d4 * 4 + 1][r] = va[it].y;
            As[0][d4 * 4 + 2][r] = va[it].z; As[0][d4 * 4 + 3][r] = va[it].w;
            Bs[0][d4 * 4 + 0][r] = vb[it].x; Bs[0][d4 * 4 + 1][r] = vb[it].y;
            Bs[0][d4 * 4 + 2][r] = vb[it].z; Bs[0][d4 * 4 + 3][r] = vb[it].w;
        }
    }

    const int NCH = (KHALF / BK) * 8; // 128 chunks (16 kt * 8 d-chunks)
    for (int c = 0; c < NCH; c++) {
        const int buf = c & 1;
        __syncthreads();
        if (c + 1 < NCH) {
            int kt = (c + 1) >> 3, ch = (c + 1) & 7;
            float4 va[4], vb[4];
#pragma unroll
            for (int it = 0; it < 4; it++) {
                int f = it * 256 + tid;
                int r = f >> 3, d4 = f & 7;
                va[it] = *(const float4*)&z[(size_t)(rowBase + r) * D_DIM + ch * DC + d4 * 4];
                vb[it] = *(const float4*)&w[(size_t)(kBase0 + kt * BK + r) * D_DIM + ch * DC + d4 * 4];
            }
            int nb = buf ^ 1;
#pragma unroll
            for (int it = 0; it < 4; it++) {
                int f = it * 256 + tid;
                int r = f >> 3, d4 = f & 7;
                As[nb][d4 * 4 + 0][r] = va[it].x; As[nb][d4 * 4 + 1][r] = va[it].y;
                As[nb][d4 * 4 + 2][r] = va[it].z; As[nb][d4 * 4 + 3][r] = va[it].w;
                Bs[nb][d4 * 4 + 0][r] = vb[it].x; Bs[nb][d4 * 4 + 1][r] = vb[it].y;
                Bs[nb][d4 * 4 + 2][r] = vb[it].z; Bs[nb][d4 * 4 + 3][r] = vb[it].w;
            }
        }
        if ((c & 7) == 0) {
#pragma unroll
            for (int i = 0; i < 8; i++)
#pragma unroll
                for (int j = 0; j < 8; j++) acc[i][j] = 0.0f;
            int kt = c >> 3;
#pragma unroll
            for (int j = 0; j < 8; j++) e2c[j] = e2[kBase0 + kt * BK + tx * 8 + j];
        }
#pragma unroll
        for (int dd = 0; dd < DC; dd++) {
            float4 a0 = *(const float4*)&As[buf][dd][ty * 8];
            float4 a1 = *(const float4*)&As[buf][dd][ty * 8 + 4];
            float4 b0 = *(const float4*)&Bs[buf][dd][tx * 8];
            float4 b1 = *(const float4*)&Bs[buf][dd][tx * 8 + 4];
            float av[8] = {a0.x, a0.y, a0.z, a0.w, a1.x, a1.y, a1.z, a1.w};
            float bv[8] = {b0.x, b0.y, b0.z, b0.w, b1.x, b1.y, b1.z, b1.w};
#pragma unroll
            for (int i = 0; i < 8; i++)
#pragma unroll
                for (int j = 0; j < 8; j++)
                    acc[i][j] = __builtin_fmaf(av[i], bv[j], acc[i][j]);
        }
        if ((c & 7) == 7) {
            int kt = c >> 3;
#pragma unroll
            for (int i = 0; i < 8; i++) {
#pragma unroll
                for (int j = 0; j < 8; j++) {
                    // replicate np rounding: fl(fl(z2 - 2t) + e2); 2t exact
                    float u = z2r[i] - 2.0f * acc[i][j];
                    float dv = u + e2c[j];
                    int kk = kBase0 + kt * BK + tx * 8 + j;
                    if (dv < best[i]) { best[i] = dv; bestk[i] = kk; } // ascending k => first-min
                }
            }
        }
    }

    __syncthreads();
    float* redD = &As[0][0][0];      // 128*16 floats
    int*   redK = (int*)&Bs[0][0][0];
#pragma unroll
    for (int i = 0; i < 8; i++) {
        redD[(ty * 8 + i) * 16 + tx] = best[i];
        redK[(ty * 8 + i) * 16 + tx] = bestk[i];
    }
    __syncthreads();
    if (tid < BN) {
        float bd = redD[tid * 16]; int bk = redK[tid * 16];
#pragma unroll
        for (int t = 1; t < 16; t++) {
            float dv = redD[tid * 16 + t]; int kv = redK[tid * 16 + t];
            if (dv < bd || (dv == bd && kv < bk)) { bd = dv; bk = kv; }
        }
        part_d[blockIdx.y * N_ROWS + rowBase + tid] = bd;
        part_k[blockIdx.y * N_ROWS + rowBase + tid] = bk;
    }
}

// ---------------------------------------------------------------------------
// K3: merge K-halves, gather z_q, STE output fl(z + fl(zq - z)), loss partials,
// counts and dw via atomics. One block (256 thr) per row.
// ---------------------------------------------------------------------------
__global__ void k3_scatter(const float* __restrict__ z, const float* __restrict__ w,
                           const float* __restrict__ part_d, const int* __restrict__ part_k,
                           float* __restrict__ counts, float* __restrict__ lossp,
                           float* __restrict__ dw, float* __restrict__ out_zq,
                           float* __restrict__ out_idx)
{
#pragma clang fp contract(off)
    const int n = blockIdx.x;
    const int t = threadIdx.x;
    float d0 = part_d[n], d1 = part_d[N_ROWS + n];
    int k0 = part_k[n], k1 = part_k[N_ROWS + n];
    int idx = (d1 < d0) ? k1 : k0;   // tie -> lower k (k0 < k1 always)
    if (t == 0) {
        out_idx[n] = (float)idx;
        atomicAdd(&counts[idx], 1.0f);
    }
    float zv = z[(size_t)n * D_DIM + t];
    float wq = w[(size_t)idx * D_DIM + t];
    out_zq[(size_t)n * D_DIM + t] = zv + (wq - zv);
    float df = zv - wq;
    float sq = df * df;
    atomicAdd(&dw[(size_t)idx * D_DIM + t], zv);

    __shared__ float red[256];
    red[t] = sq; __syncthreads();
    for (int s = 128; s > 0; s >>= 1) {
        if (t < s) red[t] += red[t + s];
        __syncthreads();
    }
    if (t == 0) lossp[n] = red[0];
}

// ---------------------------------------------------------------------------
// K4: vq_loss finalize + new_cs (Laplace smoothing). Single block, 1024 thr.
// ---------------------------------------------------------------------------
__global__ void k4_cs(const float* __restrict__ lossp, const float* __restrict__ counts,
                      const float* __restrict__ cs_in, float* __restrict__ out_loss,
                      float* __restrict__ out_cs)
{
#pragma clang fp contract(off)
    const int t = threadIdx.x;
    __shared__ float red[1024];
    __shared__ float pre[K_CODES];

    float s = 0.0f;
    for (int i = t; i < N_ROWS; i += 1024) s += lossp[i];
    red[t] = s; __syncthreads();
    for (int st = 512; st > 0; st >>= 1) {
        if (t < st) red[t] += red[t + st];
        __syncthreads();
    }
    if (t == 0) out_loss[0] = 0.25f * (red[0] / 8388608.0f);
    __syncthreads();

    const float DEC = 0.99f;
    const float OMD = (float)(1.0 - 0.99);      // matches np's fp64->fp32 scalar
    float mine[4];
#pragma unroll
    for (int q = 0; q < 4; q++) {
        int k = t + q * 1024;
        float t1 = DEC * cs_in[k];
        float t2 = OMD * counts[k];
        float p = t1 + t2;
        pre[k] = p; mine[q] = p;
    }
    float psum = (mine[0] + mine[1]) + (mine[2] + mine[3]);
    red[t] = psum; __syncthreads();
    for (int st = 512; st > 0; st >>= 1) {
        if (t < st) red[t] += red[t + st];
        __syncthreads();
    }
    float nsum = red[0];
    const float KEPS = (float)(4096.0 * 1e-5);
    float denom = nsum + KEPS;
#pragma unroll
    for (int q = 0; q < 4; q++) {
        int k = t + q * 1024;
        float v = ((pre[k] + 1e-5f) / denom) * nsum;
        out_cs[k] = v;
    }
}

// ---------------------------------------------------------------------------
// K5: new_ema_w = 0.99*ema_w + 0.01*dw ; new_weight = new_ema_w / new_cs[k]
// ---------------------------------------------------------------------------
__global__ void k5_emaw(const float* __restrict__ ema_w, const float* __restrict__ dw,
                        const float* __restrict__ newcs, float* __restrict__ out_w,
                        float* __restrict__ out_emaw)
{
#pragma clang fp contract(off)
    const int i = blockIdx.x * 256 + threadIdx.x;
    const int k = i >> 8;
    const float OMD = (float)(1.0 - 0.99);
    float t1 = 0.99f * ema_w[i];
    float t2 = OMD * dw[i];
    float ne = t1 + t2;
    out_emaw[i] = ne;
    out_w[i] = ne / newcs[k];
}

extern "C" void kernel_launch(void* const* d_in, const int* in_sizes, int n_in,
                              void* d_out, int out_size, void* d_ws, size_t ws_size,
                              hipStream_t stream)
{
    const float* z    = (const float*)d_in[0];
    const float* w    = (const float*)d_in[1];
    const float* cs   = (const float*)d_in[2];
    const float* emaw = (const float*)d_in[3];

    float* out      = (float*)d_out;
    float* out_zq   = out;                    // 8388608
    float* out_idx  = out + 8388608;          // 32768
    float* out_loss = out + 8421376;          // 1
    float* out_w    = out + 8421377;          // 1048576
    float* out_cs   = out + 9469953;          // 4096
    float* out_emaw = out + 9474049;          // 1048576

    char* ws = (char*)d_ws;
    float* counts = (float*)(ws + WS_COUNTS);
    float* lossp  = (float*)(ws + WS_LOSSP);
    float* part_d = (float*)(ws + WS_PARTD);
    int*   part_k = (int*)  (ws + WS_PARTK);
    float* dw     = (float*)(ws + WS_DW);
    float* z2     = (float*)(ws + WS_Z2);
    float* e2     = (float*)(ws + WS_E2);

    hipMemsetAsync(counts, 0, K_CODES * sizeof(float), stream);
    hipMemsetAsync(dw, 0, (size_t)K_CODES * D_DIM * sizeof(float), stream);

    k1_norms<<<(N_ROWS + K_CODES) / 256, 256, 0, stream>>>(z, w, z2, e2);

    dim3 g2(N_ROWS / BN, 2);
    k2_argmin<<<g2, 256, 0, stream>>>(z, w, z2, e2, part_d, part_k);

    k3_scatter<<<N_ROWS, 256, 0, stream>>>(z, w, part_d, part_k, counts, lossp,
                                           dw, out_zq, out_idx);

    k4_cs<<<1, 1024, 0, stream>>>(lossp, counts, cs, out_loss, out_cs);

    k5_emaw<<<K_CODES, 256, 0, stream>>>(emaw, dw, out_cs, out_w, out_emaw);
}